// Round 1
// baseline (157.450 us; speedup 1.0000x reference)
//
#include <hip/hip_runtime.h>
#include <math.h>

#define C_CH   256
#define HW     4096            // H*W = 64*64
#define B_N    32
#define BC     (B_N * C_CH)    // 8192 (b,c) slabs
#define N_PER_CH (B_N * HW)    // 131072 elements reduced per channel
#define N_TOT  ((size_t)BC * HW) // 33554432 elements per plane
#define EPS_BN 1e-5f

// ---------------------------------------------------------------------------
// Kernel 1: per-(b,c) slab partial sums.  Each slab is 4096 contiguous floats
// at offset bc*4096 in both x_real and x_imag.  256 threads, float4 loads,
// deterministic tree reduction (no float atomics).
// part layout: part[k*BC + bc], k in {sr, si, srr, sii, sri}
// ---------------------------------------------------------------------------
__global__ __launch_bounds__(256) void cbn_partials(
    const float* __restrict__ xr, const float* __restrict__ xi,
    float* __restrict__ part)
{
    const int bc = blockIdx.x;
    const int t  = threadIdx.x;
    const float4* r4 = reinterpret_cast<const float4*>(xr + (size_t)bc * HW);
    const float4* i4 = reinterpret_cast<const float4*>(xi + (size_t)bc * HW);

    float sr = 0.f, si = 0.f, srr = 0.f, sii = 0.f, sri = 0.f;
#pragma unroll
    for (int k = 0; k < (HW / 4) / 256; ++k) {   // 4 iterations
        float4 a = r4[t + k * 256];
        float4 b = i4[t + k * 256];
        sr  += a.x + a.y + a.z + a.w;
        si  += b.x + b.y + b.z + b.w;
        srr += a.x * a.x + a.y * a.y + a.z * a.z + a.w * a.w;
        sii += b.x * b.x + b.y * b.y + b.z * b.z + b.w * b.w;
        sri += a.x * b.x + a.y * b.y + a.z * b.z + a.w * b.w;
    }

    // wave-64 butterfly-down reduce
#pragma unroll
    for (int off = 32; off > 0; off >>= 1) {
        sr  += __shfl_down(sr,  off);
        si  += __shfl_down(si,  off);
        srr += __shfl_down(srr, off);
        sii += __shfl_down(sii, off);
        sri += __shfl_down(sri, off);
    }

    __shared__ float red[5][4];
    const int wave = t >> 6;
    if ((t & 63) == 0) {
        red[0][wave] = sr;  red[1][wave] = si;
        red[2][wave] = srr; red[3][wave] = sii; red[4][wave] = sri;
    }
    __syncthreads();
    if (t == 0) {
        part[0 * BC + bc] = red[0][0] + red[0][1] + red[0][2] + red[0][3];
        part[1 * BC + bc] = red[1][0] + red[1][1] + red[1][2] + red[1][3];
        part[2 * BC + bc] = red[2][0] + red[2][1] + red[2][2] + red[2][3];
        part[3 * BC + bc] = red[3][0] + red[3][1] + red[3][2] + red[3][3];
        part[4 * BC + bc] = red[4][0] + red[4][1] + red[4][2] + red[4][3];
    }
}

// ---------------------------------------------------------------------------
// Kernel 2: fold stats + whitening + affine into 6 per-channel coefficients.
// 1 block of 256 threads; thread c handles channel c (coalesced partial reads).
// coef layout: coef[k*C_CH + c], k in {Ar, Br, Cr, Ai, Bi, Ci}
// ---------------------------------------------------------------------------
__global__ __launch_bounds__(256) void cbn_coeffs(
    const float* __restrict__ part,
    const float* __restrict__ weight,   // [2,2,C]
    const float* __restrict__ bias,     // [2,C]
    float* __restrict__ coef)
{
    const int c = threadIdx.x;
    float sr = 0.f, si = 0.f, srr = 0.f, sii = 0.f, sri = 0.f;
    for (int b = 0; b < B_N; ++b) {
        const int bc = b * C_CH + c;
        sr  += part[0 * BC + bc];
        si  += part[1 * BC + bc];
        srr += part[2 * BC + bc];
        sii += part[3 * BC + bc];
        sri += part[4 * BC + bc];
    }
    const float invN = 1.0f / (float)N_PER_CH;
    const float mur = sr * invN;
    const float mui = si * invN;
    const float Vrr = srr * invN - mur * mur + EPS_BN;
    const float Vii = sii * invN - mui * mui + EPS_BN;
    const float Vri = sri * invN - mur * mui;

    const float s      = sqrtf(Vrr * Vii - Vri * Vri);
    const float tt     = sqrtf(Vrr + Vii + 2.0f * s);
    const float inv_st = 1.0f / (s * tt);
    const float Rrr = (Vii + s) * inv_st;
    const float Rii = (Vrr + s) * inv_st;
    const float Rri = -Vri * inv_st;

    const float w00 = weight[0 * C_CH + c];
    const float w01 = weight[1 * C_CH + c];
    const float w10 = weight[2 * C_CH + c];
    const float w11 = weight[3 * C_CH + c];
    const float b0  = bias[c];
    const float b1  = bias[C_CH + c];

    const float Ar = w00 * Rrr + w01 * Rri;
    const float Br = w00 * Rri + w01 * Rii;
    const float Ai = w10 * Rrr + w11 * Rri;
    const float Bi = w10 * Rri + w11 * Rii;

    coef[0 * C_CH + c] = Ar;
    coef[1 * C_CH + c] = Br;
    coef[2 * C_CH + c] = b0 - Ar * mur - Br * mui;
    coef[3 * C_CH + c] = Ai;
    coef[4 * C_CH + c] = Bi;
    coef[5 * C_CH + c] = b1 - Ai * mur - Bi * mui;
}

// ---------------------------------------------------------------------------
// Kernel 3: elementwise apply.  out_r = Ar*x_r + Br*x_i + Cr (imag likewise).
// float4 grid-stride; channel uniform within each float4 (HW=4096 % 4 == 0).
// Output layout [2, B, C, H, W]: real plane first, imag plane at +N_TOT.
// ---------------------------------------------------------------------------
__global__ __launch_bounds__(256) void cbn_apply(
    const float* __restrict__ xr, const float* __restrict__ xi,
    const float* __restrict__ coef, float* __restrict__ out)
{
    const float4* r4 = reinterpret_cast<const float4*>(xr);
    const float4* i4 = reinterpret_cast<const float4*>(xi);
    float4* o4 = reinterpret_cast<float4*>(out);
    const int n4 = (int)(N_TOT / 4);   // 8388608

    for (int i = blockIdx.x * blockDim.x + threadIdx.x; i < n4;
         i += gridDim.x * blockDim.x) {
        const int c = (i >> 10) & (C_CH - 1);   // elem idx = 4i; c = (4i>>12)&255
        const float Ar = coef[0 * C_CH + c];
        const float Br = coef[1 * C_CH + c];
        const float Cr = coef[2 * C_CH + c];
        const float Ai = coef[3 * C_CH + c];
        const float Bi = coef[4 * C_CH + c];
        const float Ci = coef[5 * C_CH + c];

        const float4 a = r4[i];
        const float4 b = i4[i];
        float4 u, v;
        u.x = Ar * a.x + Br * b.x + Cr;
        u.y = Ar * a.y + Br * b.y + Cr;
        u.z = Ar * a.z + Br * b.z + Cr;
        u.w = Ar * a.w + Br * b.w + Cr;
        v.x = Ai * a.x + Bi * b.x + Ci;
        v.y = Ai * a.y + Bi * b.y + Ci;
        v.z = Ai * a.z + Bi * b.z + Ci;
        v.w = Ai * a.w + Bi * b.w + Ci;
        o4[i]      = u;
        o4[n4 + i] = v;
    }
}

extern "C" void kernel_launch(void* const* d_in, const int* in_sizes, int n_in,
                              void* d_out, int out_size, void* d_ws, size_t ws_size,
                              hipStream_t stream) {
    const float* xr     = (const float*)d_in[0];
    const float* xi     = (const float*)d_in[1];
    const float* weight = (const float*)d_in[2];
    const float* bias   = (const float*)d_in[3];
    float* out = (float*)d_out;

    float* part = (float*)d_ws;            // 5*BC floats = 160 KiB
    float* coef = part + 5 * BC;           // 6*C floats

    cbn_partials<<<BC, 256, 0, stream>>>(xr, xi, part);
    cbn_coeffs<<<1, 256, 0, stream>>>(part, weight, bias, coef);
    cbn_apply<<<2048, 256, 0, stream>>>(xr, xi, coef, out);
}

// Round 3
// 122.010 us; speedup vs baseline: 1.2905x; 1.2905x over previous
//
#include <hip/hip_runtime.h>
#include <math.h>

#define C_CH   256
#define HW     4096              // H*W = 64*64
#define B_N    32
#define BC     (B_N * C_CH)      // 8192 (b,c) slabs
#define N_PER_CH (B_N * HW)      // 131072 elements reduced per channel
#define N_TOT  ((size_t)BC * HW) // 33554432 elements per plane
#define EPS_BN 1e-5f

typedef float f32x4 __attribute__((ext_vector_type(4)));

// ---------------------------------------------------------------------------
// Kernel 1: per-(b,c) slab partial sums.  Each slab is 4096 contiguous floats
// at offset bc*4096 in both x_real and x_imag.  256 threads, float4 loads,
// deterministic tree reduction (no float atomics).
// part layout: part[k*BC + bc], k in {sr, si, srr, sii, sri}
// Regular (temporal) loads on purpose: they warm L3 for the apply pass.
// ---------------------------------------------------------------------------
__global__ __launch_bounds__(256) void cbn_partials(
    const float* __restrict__ xr, const float* __restrict__ xi,
    float* __restrict__ part)
{
    const int bc = blockIdx.x;
    const int t  = threadIdx.x;
    const f32x4* r4 = reinterpret_cast<const f32x4*>(xr + (size_t)bc * HW);
    const f32x4* i4 = reinterpret_cast<const f32x4*>(xi + (size_t)bc * HW);

    float sr = 0.f, si = 0.f, srr = 0.f, sii = 0.f, sri = 0.f;
#pragma unroll
    for (int k = 0; k < (HW / 4) / 256; ++k) {   // 4 iterations
        f32x4 a = r4[t + k * 256];
        f32x4 b = i4[t + k * 256];
        sr  += a.x + a.y + a.z + a.w;
        si  += b.x + b.y + b.z + b.w;
        srr += a.x * a.x + a.y * a.y + a.z * a.z + a.w * a.w;
        sii += b.x * b.x + b.y * b.y + b.z * b.z + b.w * b.w;
        sri += a.x * b.x + a.y * b.y + a.z * b.z + a.w * b.w;
    }

    // wave-64 reduce
#pragma unroll
    for (int off = 32; off > 0; off >>= 1) {
        sr  += __shfl_down(sr,  off);
        si  += __shfl_down(si,  off);
        srr += __shfl_down(srr, off);
        sii += __shfl_down(sii, off);
        sri += __shfl_down(sri, off);
    }

    __shared__ float red[5][4];
    const int wave = t >> 6;
    if ((t & 63) == 0) {
        red[0][wave] = sr;  red[1][wave] = si;
        red[2][wave] = srr; red[3][wave] = sii; red[4][wave] = sri;
    }
    __syncthreads();
    if (t == 0) {
        part[0 * BC + bc] = red[0][0] + red[0][1] + red[0][2] + red[0][3];
        part[1 * BC + bc] = red[1][0] + red[1][1] + red[1][2] + red[1][3];
        part[2 * BC + bc] = red[2][0] + red[2][1] + red[2][2] + red[2][3];
        part[3 * BC + bc] = red[3][0] + red[3][1] + red[3][2] + red[3][3];
        part[4 * BC + bc] = red[4][0] + red[4][1] + red[4][2] + red[4][3];
    }
}

// ---------------------------------------------------------------------------
// Kernel 2 (fused): per-block coefficient derivation + elementwise apply.
// One block per (b,c) slab -> channel index is block-uniform.
// Preamble: lanes 0..31 of wave 0 load the 32 per-batch partials for this
// channel, shuffle-reduce, lane 0 folds stats+whitening+affine into 6 coefs
// in LDS.  Main loop: float4 loads (L3-resident after kernel 1), FMA, and
// NON-TEMPORAL stores so the 256 MiB output stream does not evict the
// inputs from the Infinity Cache.
// Output layout [2, B, C, H, W]: real plane first, imag plane at +N_TOT.
// ---------------------------------------------------------------------------
__global__ __launch_bounds__(256) void cbn_apply(
    const float* __restrict__ xr, const float* __restrict__ xi,
    const float* __restrict__ part,
    const float* __restrict__ weight,   // [2,2,C]
    const float* __restrict__ bias,     // [2,C]
    float* __restrict__ out)
{
    const int bc = blockIdx.x;
    const int c  = bc & (C_CH - 1);
    const int t  = threadIdx.x;

    __shared__ float scoef[6];

    if (t < 64) {
        float sr = 0.f, si = 0.f, srr = 0.f, sii = 0.f, sri = 0.f;
        if (t < 32) {
            const int idx = t * C_CH + c;       // batch t, channel c
            sr  = part[0 * BC + idx];
            si  = part[1 * BC + idx];
            srr = part[2 * BC + idx];
            sii = part[3 * BC + idx];
            sri = part[4 * BC + idx];
        }
#pragma unroll
        for (int off = 16; off > 0; off >>= 1) {
            sr  += __shfl_down(sr,  off);
            si  += __shfl_down(si,  off);
            srr += __shfl_down(srr, off);
            sii += __shfl_down(sii, off);
            sri += __shfl_down(sri, off);
        }
        if (t == 0) {
            const float invN = 1.0f / (float)N_PER_CH;
            const float mur = sr * invN;
            const float mui = si * invN;
            const float Vrr = srr * invN - mur * mur + EPS_BN;
            const float Vii = sii * invN - mui * mui + EPS_BN;
            const float Vri = sri * invN - mur * mui;

            const float s      = sqrtf(Vrr * Vii - Vri * Vri);
            const float tt     = sqrtf(Vrr + Vii + 2.0f * s);
            const float inv_st = 1.0f / (s * tt);
            const float Rrr = (Vii + s) * inv_st;
            const float Rii = (Vrr + s) * inv_st;
            const float Rri = -Vri * inv_st;

            const float w00 = weight[0 * C_CH + c];
            const float w01 = weight[1 * C_CH + c];
            const float w10 = weight[2 * C_CH + c];
            const float w11 = weight[3 * C_CH + c];
            const float b0  = bias[c];
            const float b1  = bias[C_CH + c];

            const float Ar = w00 * Rrr + w01 * Rri;
            const float Br = w00 * Rri + w01 * Rii;
            const float Ai = w10 * Rrr + w11 * Rri;
            const float Bi = w10 * Rri + w11 * Rii;

            scoef[0] = Ar;
            scoef[1] = Br;
            scoef[2] = b0 - Ar * mur - Br * mui;
            scoef[3] = Ai;
            scoef[4] = Bi;
            scoef[5] = b1 - Ai * mur - Bi * mui;
        }
    }
    __syncthreads();

    const float Ar = scoef[0], Br = scoef[1], Cr = scoef[2];
    const float Ai = scoef[3], Bi = scoef[4], Ci = scoef[5];

    const size_t base = (size_t)bc * HW;
    const f32x4* r4 = reinterpret_cast<const f32x4*>(xr + base);
    const f32x4* i4 = reinterpret_cast<const f32x4*>(xi + base);
    f32x4* o4r = reinterpret_cast<f32x4*>(out + base);
    f32x4* o4i = reinterpret_cast<f32x4*>(out + N_TOT + base);

#pragma unroll
    for (int k = 0; k < (HW / 4) / 256; ++k) {   // 4 iterations
        const int j = t + k * 256;
        const f32x4 a = r4[j];
        const f32x4 b = i4[j];
        f32x4 u, v;
        u.x = Ar * a.x + Br * b.x + Cr;
        u.y = Ar * a.y + Br * b.y + Cr;
        u.z = Ar * a.z + Br * b.z + Cr;
        u.w = Ar * a.w + Br * b.w + Cr;
        v.x = Ai * a.x + Bi * b.x + Ci;
        v.y = Ai * a.y + Bi * b.y + Ci;
        v.z = Ai * a.z + Bi * b.z + Ci;
        v.w = Ai * a.w + Bi * b.w + Ci;
        __builtin_nontemporal_store(u, &o4r[j]);
        __builtin_nontemporal_store(v, &o4i[j]);
    }
}

extern "C" void kernel_launch(void* const* d_in, const int* in_sizes, int n_in,
                              void* d_out, int out_size, void* d_ws, size_t ws_size,
                              hipStream_t stream) {
    const float* xr     = (const float*)d_in[0];
    const float* xi     = (const float*)d_in[1];
    const float* weight = (const float*)d_in[2];
    const float* bias   = (const float*)d_in[3];
    float* out = (float*)d_out;

    float* part = (float*)d_ws;            // 5*BC floats = 160 KiB

    cbn_partials<<<BC, 256, 0, stream>>>(xr, xi, part);
    cbn_apply<<<BC, 256, 0, stream>>>(xr, xi, part, weight, bias, out);
}

// Round 4
// 121.611 us; speedup vs baseline: 1.2947x; 1.0033x over previous
//
#include <hip/hip_runtime.h>
#include <math.h>

#define C_CH   256
#define HW     4096              // H*W = 64*64
#define B_N    32
#define BC     (B_N * C_CH)      // 8192 (b,c) slabs
#define N_PER_CH (B_N * HW)      // 131072 elements reduced per channel
#define N_TOT  ((size_t)BC * HW) // 33554432 elements per plane
#define EPS_BN 1e-5f

typedef float f32x4 __attribute__((ext_vector_type(4)));

// ---------------------------------------------------------------------------
// Kernel 1: per-(b,c) slab partial sums (FORWARD scan order).
// part layout: part[k*BC + bc], k in {sr, si, srr, sii, sri}
// Temporal loads on purpose: they warm L3 for the (reverse) apply pass.
// ---------------------------------------------------------------------------
__global__ __launch_bounds__(256) void cbn_partials(
    const float* __restrict__ xr, const float* __restrict__ xi,
    float* __restrict__ part)
{
    const int bc = blockIdx.x;
    const int t  = threadIdx.x;
    const f32x4* r4 = reinterpret_cast<const f32x4*>(xr + (size_t)bc * HW);
    const f32x4* i4 = reinterpret_cast<const f32x4*>(xi + (size_t)bc * HW);

    float sr = 0.f, si = 0.f, srr = 0.f, sii = 0.f, sri = 0.f;
#pragma unroll
    for (int k = 0; k < (HW / 4) / 256; ++k) {   // 4 iterations
        f32x4 a = r4[t + k * 256];
        f32x4 b = i4[t + k * 256];
        sr  += a.x + a.y + a.z + a.w;
        si  += b.x + b.y + b.z + b.w;
        srr += a.x * a.x + a.y * a.y + a.z * a.z + a.w * a.w;
        sii += b.x * b.x + b.y * b.y + b.z * b.z + b.w * b.w;
        sri += a.x * b.x + a.y * b.y + a.z * b.z + a.w * b.w;
    }

    // wave-64 reduce
#pragma unroll
    for (int off = 32; off > 0; off >>= 1) {
        sr  += __shfl_down(sr,  off);
        si  += __shfl_down(si,  off);
        srr += __shfl_down(srr, off);
        sii += __shfl_down(sii, off);
        sri += __shfl_down(sri, off);
    }

    __shared__ float red[5][4];
    const int wave = t >> 6;
    if ((t & 63) == 0) {
        red[0][wave] = sr;  red[1][wave] = si;
        red[2][wave] = srr; red[3][wave] = sii; red[4][wave] = sri;
    }
    __syncthreads();
    if (t == 0) {
        part[0 * BC + bc] = red[0][0] + red[0][1] + red[0][2] + red[0][3];
        part[1 * BC + bc] = red[1][0] + red[1][1] + red[1][2] + red[1][3];
        part[2 * BC + bc] = red[2][0] + red[2][1] + red[2][2] + red[2][3];
        part[3 * BC + bc] = red[3][0] + red[3][1] + red[3][2] + red[3][3];
        part[4 * BC + bc] = red[4][0] + red[4][1] + red[4][2] + red[4][3];
    }
}

// ---------------------------------------------------------------------------
// Kernel 2 (fused): coefficient derivation + apply, in REVERSE slab order.
// Boustrophedon scan: pass 1 reads forward, this pass reads backward, so the
// most-recently-cached tail of pass 1 is read first -> L3 (256 MiB = working
// set) serves the re-read instead of thrashing.  Non-temporal output stores
// keep the 256 MiB write stream from evicting the inputs.
// Output layout [2, B, C, H, W]: real plane first, imag plane at +N_TOT.
// ---------------------------------------------------------------------------
__global__ __launch_bounds__(256) void cbn_apply(
    const float* __restrict__ xr, const float* __restrict__ xi,
    const float* __restrict__ part,
    const float* __restrict__ weight,   // [2,2,C]
    const float* __restrict__ bias,     // [2,C]
    float* __restrict__ out)
{
    const int bc = (BC - 1) - blockIdx.x;   // reverse scan
    const int c  = bc & (C_CH - 1);
    const int t  = threadIdx.x;

    __shared__ float scoef[6];

    if (t < 64) {
        float sr = 0.f, si = 0.f, srr = 0.f, sii = 0.f, sri = 0.f;
        if (t < 32) {
            const int idx = t * C_CH + c;       // batch t, channel c
            sr  = part[0 * BC + idx];
            si  = part[1 * BC + idx];
            srr = part[2 * BC + idx];
            sii = part[3 * BC + idx];
            sri = part[4 * BC + idx];
        }
#pragma unroll
        for (int off = 16; off > 0; off >>= 1) {
            sr  += __shfl_down(sr,  off);
            si  += __shfl_down(si,  off);
            srr += __shfl_down(srr, off);
            sii += __shfl_down(sii, off);
            sri += __shfl_down(sri, off);
        }
        if (t == 0) {
            const float invN = 1.0f / (float)N_PER_CH;
            const float mur = sr * invN;
            const float mui = si * invN;
            const float Vrr = srr * invN - mur * mur + EPS_BN;
            const float Vii = sii * invN - mui * mui + EPS_BN;
            const float Vri = sri * invN - mur * mui;

            const float s      = sqrtf(Vrr * Vii - Vri * Vri);
            const float tt     = sqrtf(Vrr + Vii + 2.0f * s);
            const float inv_st = 1.0f / (s * tt);
            const float Rrr = (Vii + s) * inv_st;
            const float Rii = (Vrr + s) * inv_st;
            const float Rri = -Vri * inv_st;

            const float w00 = weight[0 * C_CH + c];
            const float w01 = weight[1 * C_CH + c];
            const float w10 = weight[2 * C_CH + c];
            const float w11 = weight[3 * C_CH + c];
            const float b0  = bias[c];
            const float b1  = bias[C_CH + c];

            const float Ar = w00 * Rrr + w01 * Rri;
            const float Br = w00 * Rri + w01 * Rii;
            const float Ai = w10 * Rrr + w11 * Rri;
            const float Bi = w10 * Rri + w11 * Rii;

            scoef[0] = Ar;
            scoef[1] = Br;
            scoef[2] = b0 - Ar * mur - Br * mui;
            scoef[3] = Ai;
            scoef[4] = Bi;
            scoef[5] = b1 - Ai * mur - Bi * mui;
        }
    }
    __syncthreads();

    const float Ar = scoef[0], Br = scoef[1], Cr = scoef[2];
    const float Ai = scoef[3], Bi = scoef[4], Ci = scoef[5];

    const size_t base = (size_t)bc * HW;
    const f32x4* r4 = reinterpret_cast<const f32x4*>(xr + base);
    const f32x4* i4 = reinterpret_cast<const f32x4*>(xi + base);
    f32x4* o4r = reinterpret_cast<f32x4*>(out + base);
    f32x4* o4i = reinterpret_cast<f32x4*>(out + N_TOT + base);

#pragma unroll
    for (int k = 0; k < (HW / 4) / 256; ++k) {   // 4 iterations
        const int j = t + k * 256;
        const f32x4 a = r4[j];
        const f32x4 b = i4[j];
        f32x4 u, v;
        u.x = Ar * a.x + Br * b.x + Cr;
        u.y = Ar * a.y + Br * b.y + Cr;
        u.z = Ar * a.z + Br * b.z + Cr;
        u.w = Ar * a.w + Br * b.w + Cr;
        v.x = Ai * a.x + Bi * b.x + Ci;
        v.y = Ai * a.y + Bi * b.y + Ci;
        v.z = Ai * a.z + Bi * b.z + Ci;
        v.w = Ai * a.w + Bi * b.w + Ci;
        __builtin_nontemporal_store(u, &o4r[j]);
        __builtin_nontemporal_store(v, &o4i[j]);
    }
}

extern "C" void kernel_launch(void* const* d_in, const int* in_sizes, int n_in,
                              void* d_out, int out_size, void* d_ws, size_t ws_size,
                              hipStream_t stream) {
    const float* xr     = (const float*)d_in[0];
    const float* xi     = (const float*)d_in[1];
    const float* weight = (const float*)d_in[2];
    const float* bias   = (const float*)d_in[3];
    float* out = (float*)d_out;

    float* part = (float*)d_ws;            // 5*BC floats = 160 KiB

    cbn_partials<<<BC, 256, 0, stream>>>(xr, xi, part);
    cbn_apply<<<BC, 256, 0, stream>>>(xr, xi, part, weight, bias, out);
}

// Round 5
// 121.115 us; speedup vs baseline: 1.3000x; 1.0041x over previous
//
#include <hip/hip_runtime.h>
#include <math.h>

#define C_CH   256
#define HW     4096              // H*W = 64*64
#define B_N    32
#define N_PER_CH (B_N * HW)      // 131072 elements reduced per channel
#define N_TOT  ((size_t)B_N * C_CH * HW) // 33554432 elements per plane
#define EPS_BN 1e-5f

typedef float f32x4 __attribute__((ext_vector_type(4)));

// ---------------------------------------------------------------------------
// Single fused kernel: one workgroup per channel (grid=256 = 1 block/CU).
// Phase 1: read the channel's 1 MiB (32 slabs x 16 KiB x 2 planes), reduce
//          5 sums over 1024 threads, fold stats+whitening+affine into 6
//          per-channel coefficients.
// Phase 2: re-read the same 1 MiB (short reuse distance -> L2/L3 hit),
//          nt loads (last touch, don't allocate) + nt stores (don't evict).
// Output layout [2, B, C, H, W]: real plane first, imag plane at +N_TOT.
// ---------------------------------------------------------------------------
__global__ __launch_bounds__(1024) void cbn_fused(
    const float* __restrict__ xr, const float* __restrict__ xi,
    const float* __restrict__ weight,   // [2,2,C]
    const float* __restrict__ bias,     // [2,C]
    float* __restrict__ out)
{
    const int c = blockIdx.x;
    const int t = threadIdx.x;
    const f32x4* r4 = reinterpret_cast<const f32x4*>(xr);
    const f32x4* i4 = reinterpret_cast<const f32x4*>(xi);

    // ---- phase 1: per-thread accumulation over 32 slabs -------------------
    float sr = 0.f, si = 0.f, srr = 0.f, sii = 0.f, sri = 0.f;
#pragma unroll 4
    for (int j = 0; j < B_N; ++j) {
        const size_t idx = ((size_t)(j * C_CH + c) << 10) + t;  // slab j, float4 t
        const f32x4 a = r4[idx];
        const f32x4 b = i4[idx];
        sr  += a.x + a.y + a.z + a.w;
        si  += b.x + b.y + b.z + b.w;
        srr += a.x * a.x + a.y * a.y + a.z * a.z + a.w * a.w;
        sii += b.x * b.x + b.y * b.y + b.z * b.z + b.w * b.w;
        sri += a.x * b.x + a.y * b.y + a.z * b.z + a.w * b.w;
    }

    // wave-64 reduce
#pragma unroll
    for (int off = 32; off > 0; off >>= 1) {
        sr  += __shfl_down(sr,  off);
        si  += __shfl_down(si,  off);
        srr += __shfl_down(srr, off);
        sii += __shfl_down(sii, off);
        sri += __shfl_down(sri, off);
    }

    __shared__ float red[5][16];
    __shared__ float scoef[6];
    const int wave = t >> 6;
    if ((t & 63) == 0) {
        red[0][wave] = sr;  red[1][wave] = si;
        red[2][wave] = srr; red[3][wave] = sii; red[4][wave] = sri;
    }
    __syncthreads();

    if (t < 64) {
        float v0 = 0.f, v1 = 0.f, v2 = 0.f, v3 = 0.f, v4 = 0.f;
        if (t < 16) {
            v0 = red[0][t]; v1 = red[1][t]; v2 = red[2][t];
            v3 = red[3][t]; v4 = red[4][t];
        }
#pragma unroll
        for (int off = 8; off > 0; off >>= 1) {
            v0 += __shfl_down(v0, off);
            v1 += __shfl_down(v1, off);
            v2 += __shfl_down(v2, off);
            v3 += __shfl_down(v3, off);
            v4 += __shfl_down(v4, off);
        }
        if (t == 0) {
            const float invN = 1.0f / (float)N_PER_CH;
            const float mur = v0 * invN;
            const float mui = v1 * invN;
            const float Vrr = v2 * invN - mur * mur + EPS_BN;
            const float Vii = v3 * invN - mui * mui + EPS_BN;
            const float Vri = v4 * invN - mur * mui;

            const float s      = sqrtf(Vrr * Vii - Vri * Vri);
            const float tt     = sqrtf(Vrr + Vii + 2.0f * s);
            const float inv_st = 1.0f / (s * tt);
            const float Rrr = (Vii + s) * inv_st;
            const float Rii = (Vrr + s) * inv_st;
            const float Rri = -Vri * inv_st;

            const float w00 = weight[0 * C_CH + c];
            const float w01 = weight[1 * C_CH + c];
            const float w10 = weight[2 * C_CH + c];
            const float w11 = weight[3 * C_CH + c];
            const float b0  = bias[c];
            const float b1  = bias[C_CH + c];

            const float Ar = w00 * Rrr + w01 * Rri;
            const float Br = w00 * Rri + w01 * Rii;
            const float Ai = w10 * Rrr + w11 * Rri;
            const float Bi = w10 * Rri + w11 * Rii;

            scoef[0] = Ar;
            scoef[1] = Br;
            scoef[2] = b0 - Ar * mur - Br * mui;
            scoef[3] = Ai;
            scoef[4] = Bi;
            scoef[5] = b1 - Ai * mur - Bi * mui;
        }
    }
    __syncthreads();

    const float Ar = scoef[0], Br = scoef[1], Cr = scoef[2];
    const float Ai = scoef[3], Bi = scoef[4], Ci = scoef[5];

    // ---- phase 2: re-read (cache-hot), apply, nt-store --------------------
    f32x4* o4 = reinterpret_cast<f32x4*>(out);
    const size_t n4 = N_TOT / 4;

#pragma unroll 4
    for (int j = 0; j < B_N; ++j) {
        const size_t idx = ((size_t)(j * C_CH + c) << 10) + t;
        const f32x4 a = __builtin_nontemporal_load(&r4[idx]);
        const f32x4 b = __builtin_nontemporal_load(&i4[idx]);
        f32x4 u, v;
        u.x = Ar * a.x + Br * b.x + Cr;
        u.y = Ar * a.y + Br * b.y + Cr;
        u.z = Ar * a.z + Br * b.z + Cr;
        u.w = Ar * a.w + Br * b.w + Cr;
        v.x = Ai * a.x + Bi * b.x + Ci;
        v.y = Ai * a.y + Bi * b.y + Ci;
        v.z = Ai * a.z + Bi * b.z + Ci;
        v.w = Ai * a.w + Bi * b.w + Ci;
        __builtin_nontemporal_store(u, &o4[idx]);
        __builtin_nontemporal_store(v, &o4[n4 + idx]);
    }
}

extern "C" void kernel_launch(void* const* d_in, const int* in_sizes, int n_in,
                              void* d_out, int out_size, void* d_ws, size_t ws_size,
                              hipStream_t stream) {
    const float* xr     = (const float*)d_in[0];
    const float* xi     = (const float*)d_in[1];
    const float* weight = (const float*)d_in[2];
    const float* bias   = (const float*)d_in[3];
    float* out = (float*)d_out;

    cbn_fused<<<C_CH, 1024, 0, stream>>>(xr, xi, weight, bias, out);
}